// Round 2
// baseline (1797.543 us; speedup 1.0000x reference)
//
#include <hip/hip_runtime.h>
#include <hip/hip_bf16.h>

// Problem constants
#define VV 3
#define NN 8192
#define HH 128
#define ADIM 64
#define FOUT 128

typedef short bf16x8 __attribute__((ext_vector_type(8)));
typedef float f32x4 __attribute__((ext_vector_type(4)));

__device__ __forceinline__ float bf2f(ushort u) {
    union { unsigned int i; float f; } x; x.i = ((unsigned int)u) << 16; return x.f;
}
__device__ __forceinline__ ushort f2bf(float f) {
    union { float f; unsigned int i; } x; x.f = f;
    unsigned int r = (x.i + 0x7FFFu + ((x.i >> 16) & 1u)) >> 16;
    return (ushort)r;
}

// ---------------------------------------------------------------------------
// zero a small float region (summ + attn scratch); ws is poisoned every call
__global__ void zero_k(float* p, int n) {
    int i = blockIdx.x * blockDim.x + threadIdx.x;
    if (i < n) p[i] = 0.0f;
}

// ---------------------------------------------------------------------------
// deg pass: dinv[v*N+i] = rsqrt(1 + #nonzero offdiag of row i)  (diag forced 1)
__global__ __launch_bounds__(256) void deg_k(const int* __restrict__ adj, float* __restrict__ dinv) {
    const int w = threadIdx.x >> 6, lane = threadIdx.x & 63;
    const long rowg = (long)blockIdx.x * 4 + w;             // 0..V*N-1
    const int i = (int)(rowg & (NN - 1));
    const int* row = adj + rowg * NN;
    int cnt = 0;
    #pragma unroll 4
    for (int it = 0; it < 32; it++) {
        const int4 v = *(const int4*)(row + it * 256 + lane * 4);
        cnt += (v.x != 0) + (v.y != 0) + (v.z != 0) + (v.w != 0);
    }
    for (int off = 32; off; off >>= 1) cnt += __shfl_down(cnt, off);
    if (lane == 0) {
        int self = (row[i] != 0) ? 1 : 0;
        dinv[rowg] = rsqrtf((float)(cnt + 1 - self));
    }
}

// ---------------------------------------------------------------------------
// transpose (R x C) -> (C x R) per z, optional per-input-row scale (dinv).
// INF32: input is float32 (weights); else input is bf16 ushort (ws buffers).
// Output is always bf16 ushort.
template<int INF32>
__global__ void transpose_scale_k(const void* __restrict__ in_, ushort* __restrict__ out,
                                  int R, int C, const float* __restrict__ scale, int scale_z) {
    __shared__ ushort tile[32][33];
    const long zo = (long)blockIdx.z * R * C;
    const int c0 = blockIdx.x * 32, r0 = blockIdx.y * 32;
    const int t = threadIdx.x;
    #pragma unroll
    for (int p = 0; p < 4; p++) {
        int e = p * 256 + t; int row = e >> 5, col = e & 31;
        long idx = zo + (long)(r0 + row) * C + c0 + col;
        float x = INF32 ? ((const float*)in_)[idx] : bf2f(((const ushort*)in_)[idx]);
        if (scale) x *= scale[(long)blockIdx.z * scale_z + r0 + row];
        tile[row][col] = f2bf(x);
    }
    __syncthreads();
    #pragma unroll
    for (int p = 0; p < 4; p++) {
        int e = p * 256 + t; int row = e >> 5, col = e & 31;   // row indexes C-dim now
        out[zo + (long)(c0 + row) * R + r0 + col] = tile[col][row];
    }
}

// ---------------------------------------------------------------------------
// Generic 128x128-tile MFMA GEMM, BK=32, 256 threads (4 waves, 64x64 each).
// AMODE 0: A = int32 adjacency (binary, diag forced 1), lda = N
// AMODE 1: A = bf16 row-major (ws), lda given
// AMODE 2: A = h (V,N,H) bf16 (ws), K runs over v*H+h', scaled by attn[v]
// EPI 0: relu(dinv[row]*acc + bias[z,col]) ; EPI 1: dinv[row]*acc
// EPI 2: relu(acc + bias[col])             ; EPI 3: acc + bias[col]
// OUTF32 1: store f32; else store bf16 ushort
template<int AMODE, int EPI, int OUTF32>
__global__ __launch_bounds__(256) void gemm_k(
    const void* __restrict__ Aany, long a_zs, int lda,
    const ushort* __restrict__ Bt, long b_zs, int ldb,
    void* __restrict__ Cc, long c_zs, int ldc,
    int Ktot,
    const float* __restrict__ dinv, int dinv_zs,
    const float* __restrict__ bias, int bias_zs,
    const float* __restrict__ attnp)
{
    __shared__ __align__(16) ushort As[128][40];   // +8 pad; rows stay 16B-aligned
    __shared__ __align__(16) ushort Bs[128][40];
    const int tid = threadIdx.x;
    const int bx = blockIdx.x, by = blockIdx.y, z = blockIdx.z;
    const int m0 = by * 128, n0 = bx * 128;
    const int lane = tid & 63, w = tid >> 6, wr = w >> 1, wc = w & 1;
    f32x4 acc[4][4] = {};
    float att0 = 0.f, att1 = 0.f, att2 = 0.f;
    if (AMODE == 2) { att0 = attnp[0]; att1 = attnp[1]; att2 = attnp[2]; }
    const int* Ai = (const int*)Aany + (long)z * (AMODE == 0 ? a_zs : 0);
    const ushort* Ab = (const ushort*)Aany + (long)z * (AMODE == 1 ? a_zs : 0);
    const ushort* Btz = Bt + (long)z * b_zs;

    for (int k0 = 0; k0 < Ktot; k0 += 32) {
        if (AMODE == 0) {
            #pragma unroll
            for (int p = 0; p < 4; p++) {
                int c = p * 256 + tid;
                int row = c >> 3, q = c & 7;
                int gr = m0 + row, gc = k0 + q * 4;
                const int4 v = *(const int4*)(Ai + (long)gr * lda + gc);
                ushort4 o;
                o.x = (v.x != 0 || gc + 0 == gr) ? (ushort)0x3F80 : (ushort)0;
                o.y = (v.y != 0 || gc + 1 == gr) ? (ushort)0x3F80 : (ushort)0;
                o.z = (v.z != 0 || gc + 2 == gr) ? (ushort)0x3F80 : (ushort)0;
                o.w = (v.w != 0 || gc + 3 == gr) ? (ushort)0x3F80 : (ushort)0;
                *(ushort4*)&As[row][q * 4] = o;
            }
        } else if (AMODE == 1) {
            #pragma unroll
            for (int p = 0; p < 2; p++) {
                int c = p * 256 + tid;
                int row = c >> 2, q = c & 3;
                *(int4*)&As[row][q * 8] = *(const int4*)(Ab + (long)(m0 + row) * lda + k0 + q * 8);
            }
        } else {
            #pragma unroll
            for (int p = 0; p < 2; p++) {
                int c = p * 256 + tid;
                int row = c >> 2, q = c & 3;
                int kk = k0 + q * 8;
                int v = kk >> 7, ko = kk & 127;
                int4 raw = *(const int4*)((const ushort*)Aany + (long)v * a_zs + (long)(m0 + row) * HH + ko);
                float sc = (v == 0) ? att0 : (v == 1 ? att1 : att2);
                __align__(16) ushort us[8];
                *(int4*)us = raw;
                #pragma unroll
                for (int e = 0; e < 8; e++) us[e] = f2bf(bf2f(us[e]) * sc);
                *(int4*)&As[row][q * 8] = *(int4*)us;
            }
        }
        #pragma unroll
        for (int p = 0; p < 2; p++) {
            int c = p * 256 + tid;
            int n = c >> 2, q = c & 3;
            *(int4*)&Bs[n][q * 8] = *(const int4*)(Btz + (long)(n0 + n) * ldb + k0 + q * 8);
        }
        __syncthreads();
        bf16x8 af[4], bfr[4];
        #pragma unroll
        for (int mi = 0; mi < 4; mi++)
            af[mi] = *(const bf16x8*)&As[wr * 64 + mi * 16 + (lane & 15)][(lane >> 4) * 8];
        #pragma unroll
        for (int ni = 0; ni < 4; ni++)
            bfr[ni] = *(const bf16x8*)&Bs[wc * 64 + ni * 16 + (lane & 15)][(lane >> 4) * 8];
        #pragma unroll
        for (int mi = 0; mi < 4; mi++)
            #pragma unroll
            for (int ni = 0; ni < 4; ni++)
                acc[mi][ni] = __builtin_amdgcn_mfma_f32_16x16x32_bf16(af[mi], bfr[ni], acc[mi][ni], 0, 0, 0);
        __syncthreads();
    }

    #pragma unroll
    for (int mi = 0; mi < 4; mi++) {
        int rbase = m0 + wr * 64 + mi * 16 + ((lane >> 4) << 2);
        #pragma unroll
        for (int ni = 0; ni < 4; ni++) {
            int col = n0 + wc * 64 + ni * 16 + (lane & 15);
            #pragma unroll
            for (int r = 0; r < 4; r++) {
                int grow = rbase + r;
                float vv = acc[mi][ni][r];
                if (EPI == 0 || EPI == 1) vv *= dinv[(long)z * dinv_zs + grow];
                if (EPI == 0) vv += bias[z * bias_zs + col];
                if (EPI == 2 || EPI == 3) vv += bias[col];
                if (EPI == 0 || EPI == 2) vv = fmaxf(vv, 0.0f);
                if (OUTF32) ((float*)Cc + (long)z * c_zs)[(long)grow * ldc + col] = vv;
                else        ((ushort*)Cc + (long)z * c_zs)[(long)grow * ldc + col] = f2bf(vv);
            }
        }
    }
}

// ---------------------------------------------------------------------------
// copy h2 (ws bf16) -> h output region (f32) + column partial sums
// (atomicAdd into summ[v*H+col])
__global__ __launch_bounds__(256) void summ_copy_k(const ushort* __restrict__ h2,
                                                   float* __restrict__ outh,
                                                   float* __restrict__ summ) {
    const int rowbase = blockIdx.x * 64;
    const int z = rowbase >> 13;
    const int col = threadIdx.x & 127, half = threadIdx.x >> 7;
    float s = 0.0f;
    for (int r = half; r < 64; r += 2) {
        long idx = (long)(rowbase + r) * HH + col;
        float v = bf2f(h2[idx]);
        outh[idx] = v;
        s += v;
    }
    atomicAdd(&summ[z * HH + col], s);
}

// ---------------------------------------------------------------------------
// attention: summ(sum)/N -> tanh(@Wa1+ba1)@Wa2+ba2 -> softmax over V
__global__ __launch_bounds__(256) void attn_k(const float* __restrict__ summ,
                                              const float* __restrict__ Wa1,
                                              const float* __restrict__ ba1,
                                              const float* __restrict__ Wa2,
                                              const float* __restrict__ ba2,
                                              float* __restrict__ attnws,
                                              float* __restrict__ out_attn) {
    __shared__ float sc[VV];
    const int tid = threadIdx.x;
    if (tid < VV * 64) {
        const int v = tid >> 6, a = tid & 63;
        float s = ba1[a];
        const float invN = 1.0f / (float)NN;
        #pragma unroll 4
        for (int h = 0; h < HH; h++) s += summ[v * HH + h] * invN * Wa1[h * ADIM + a];
        float p = tanhf(s) * Wa2[a];
        for (int off = 32; off; off >>= 1) p += __shfl_down(p, off);
        if (a == 0) sc[v] = p + ba2[0];
    }
    __syncthreads();
    if (tid == 0) {
        float m = fmaxf(sc[0], fmaxf(sc[1], sc[2]));
        float e0 = expf(sc[0] - m), e1 = expf(sc[1] - m), e2 = expf(sc[2] - m);
        float inv = 1.0f / (e0 + e1 + e2);
        attnws[0] = e0 * inv; attnws[1] = e1 * inv; attnws[2] = e2 * inv;
        out_attn[0] = e0 * inv; out_attn[1] = e1 * inv; out_attn[2] = e2 * inv;
    }
}

// ---------------------------------------------------------------------------
extern "C" void kernel_launch(void* const* d_in, const int* in_sizes, int n_in,
                              void* d_out, int out_size, void* d_ws, size_t ws_size,
                              hipStream_t stream) {
    const int*   adj = (const int*)d_in[0];
    const float* W1  = (const float*)d_in[1];
    const float* b1  = (const float*)d_in[2];
    const float* W2  = (const float*)d_in[3];
    const float* b2  = (const float*)d_in[4];
    const float* Wa1 = (const float*)d_in[5];
    const float* ba1 = (const float*)d_in[6];
    const float* Wa2 = (const float*)d_in[7];
    const float* ba2 = (const float*)d_in[8];
    const float* Wf1 = (const float*)d_in[9];
    const float* bf1 = (const float*)d_in[10];
    const float* Wf2 = (const float*)d_in[11];
    const float* bf2v = (const float*)d_in[12];

    float* out = (float*)d_out;
    float* out_fused = out;                                  // (N, FOUT)
    float* out_attn  = out + (long)NN * FOUT;                // (V,)
    float* out_h     = out + (long)NN * FOUT + VV;           // (V,N,H)

    char* wsb = (char*)d_ws;
    const long SZ_DINV = (long)VV * NN * 4;        // 98304
    const long SZ_W1T  = (long)VV * HH * NN * 2;   // 6291456
    const long SZ_W2T  = (long)VV * HH * HH * 2;   // 98304
    const long SZ_WF1T = 256L * 384 * 2;           // 196608
    const long SZ_WF2T = 128L * 256 * 2;           // 65536
    const long SZ_VNH  = (long)VV * NN * HH * 2;   // 6291456
    const long SZ_G    = (long)NN * 256 * 2;       // 4194304
    long off = 0;
    float*  dinv  = (float*)(wsb + off);  off += SZ_DINV;
    ushort* w1t   = (ushort*)(wsb + off); off += SZ_W1T;
    ushort* w2t   = (ushort*)(wsb + off); off += SZ_W2T;
    ushort* wf1t  = (ushort*)(wsb + off); off += SZ_WF1T;
    ushort* wf2t  = (ushort*)(wsb + off); off += SZ_WF2T;
    ushort* h1    = (ushort*)(wsb + off); off += SZ_VNH;
    ushort* tbuf  = (ushort*)(wsb + off); off += SZ_VNH;
    ushort* tT    = (ushort*)(wsb + off); off += SZ_VNH;
    ushort* h2    = (ushort*)(wsb + off); off += SZ_VNH;
    ushort* G     = (ushort*)(wsb + off); off += SZ_G;
    float*  summ  = (float*)(wsb + off);  off += 1536;
    float*  attnw = (float*)(wsb + off);  off += 16;

    const long N2 = (long)NN * NN;
    const long VNH = (long)NN * HH;

    // 1) zero summ/attn scratch (ws is poisoned before every call)
    zero_k<<<1, 512, 0, stream>>>(summ, 388);
    // 2) degrees -> dinv
    deg_k<<<(VV * NN) / 4, 256, 0, stream>>>(adj, dinv);
    // 3) weight transposes (B operands staged as (Ncols x K) row-major, bf16)
    transpose_scale_k<1><<<dim3(4, 256, VV), 256, 0, stream>>>(W1, w1t, NN, HH, dinv, NN); // w1t[v][n][k]=dinv[k]*W1[v][k][n]
    transpose_scale_k<1><<<dim3(4, 4, VV), 256, 0, stream>>>(W2, w2t, HH, HH, nullptr, 0);
    transpose_scale_k<1><<<dim3(8, 12, 1), 256, 0, stream>>>(Wf1, wf1t, 384, 256, nullptr, 0);
    transpose_scale_k<1><<<dim3(4, 8, 1), 256, 0, stream>>>(Wf2, wf2t, 256, 128, nullptr, 0);
    // 4) h1 = relu(dinv_i * (A_bin @ (dinv_j*W1)) + b1)
    gemm_k<0, 0, 0><<<dim3(1, 64, VV), 256, 0, stream>>>(adj, N2, NN, w1t, VNH, NN,
                                                         h1, VNH, HH, NN, dinv, NN, b1, HH, nullptr);
    // 5) t = dinv_k * (h1 @ W2)
    gemm_k<1, 1, 0><<<dim3(1, 64, VV), 256, 0, stream>>>(h1, VNH, HH, w2t, (long)HH * HH, HH,
                                                         tbuf, VNH, HH, HH, dinv, NN, nullptr, 0, nullptr);
    // 6) tT[v][n][k] = t[v][k][n]
    transpose_scale_k<0><<<dim3(4, 256, VV), 256, 0, stream>>>(tbuf, tT, NN, HH, nullptr, 0);
    // 7) h2 = relu(dinv_i * (A_bin @ t) + b2)
    gemm_k<0, 0, 0><<<dim3(1, 64, VV), 256, 0, stream>>>(adj, N2, NN, tT, VNH, NN,
                                                         h2, VNH, HH, NN, dinv, NN, b2, HH, nullptr);
    // 8) copy h2 to output (f32) + column sums for summ
    summ_copy_k<<<(VV * NN) / 64, 256, 0, stream>>>(h2, out_h, summ);
    // 9) attention weights
    attn_k<<<1, 256, 0, stream>>>(summ, Wa1, ba1, Wa2, ba2, attnw, out_attn);
    // 10) G = relu([attn_v*h_v] @ Wf1 + bf1)   (M=8192, K=384, Ncols=256)
    gemm_k<2, 2, 0><<<dim3(2, 64, 1), 256, 0, stream>>>(h2, VNH, HH, wf1t, 0, 384,
                                                        G, 0, 256, 384, nullptr, 0, bf1, 0, attnw);
    // 11) fused = G @ Wf2 + bf2                (M=8192, K=256, Ncols=128)
    gemm_k<1, 3, 1><<<dim3(1, 64, 1), 256, 0, stream>>>(G, 0, 256, wf2t, 0, 256,
                                                        out_fused, 0, FOUT, 256, nullptr, 0, bf2v, 0, nullptr);
}

// Round 3
// 1452.687 us; speedup vs baseline: 1.2374x; 1.2374x over previous
//
#include <hip/hip_runtime.h>
#include <hip/hip_bf16.h>

// Problem constants
#define VV 3
#define NN 8192
#define HH 128
#define ADIM 64
#define FOUT 128
#define KSPLIT 4

typedef short bf16x8 __attribute__((ext_vector_type(8)));
typedef float f32x4 __attribute__((ext_vector_type(4)));

__device__ __forceinline__ float bf2f(ushort u) {
    union { unsigned int i; float f; } x; x.i = ((unsigned int)u) << 16; return x.f;
}
__device__ __forceinline__ ushort f2bf(float f) {
    union { float f; unsigned int i; } x; x.f = f;
    unsigned int r = (x.i + 0x7FFFu + ((x.i >> 16) & 1u)) >> 16;
    return (ushort)r;
}
__device__ __forceinline__ void async_cp16(const ushort* g, ushort* l) {
    __builtin_amdgcn_global_load_lds(
        (const __attribute__((address_space(1))) void*)g,
        (__attribute__((address_space(3))) void*)l, 16, 0, 0);
}

// ---------------------------------------------------------------------------
// zero a small float region (summ scratch); ws is poisoned every call
__global__ void zero_k(float* p, int n) {
    int i = blockIdx.x * blockDim.x + threadIdx.x;
    if (i < n) p[i] = 0.0f;
}

// ---------------------------------------------------------------------------
// fused deg + pack: apack[v][i][j] = bf16{0,1} binary adjacency with diag=1;
// dinv[v*N+i] = rsqrt(row_sum). One wave per row.
__global__ __launch_bounds__(256) void pack_k(const int* __restrict__ adj,
                                              ushort* __restrict__ apack,
                                              float* __restrict__ dinv) {
    const int w = threadIdx.x >> 6, lane = threadIdx.x & 63;
    const long rowg = (long)blockIdx.x * 4 + w;              // 0..V*N-1
    const int i = (int)(rowg & (NN - 1));
    const int* row = adj + rowg * NN;
    ushort* prow = apack + rowg * NN;
    int cnt = 0;
    #pragma unroll 4
    for (int it = 0; it < 32; it++) {
        const int c0 = it * 256 + lane * 4;
        const int4 v = *(const int4*)(row + c0);
        ushort4 o;
        o.x = (v.x != 0 || c0 + 0 == i) ? (ushort)0x3F80 : (ushort)0;
        o.y = (v.y != 0 || c0 + 1 == i) ? (ushort)0x3F80 : (ushort)0;
        o.z = (v.z != 0 || c0 + 2 == i) ? (ushort)0x3F80 : (ushort)0;
        o.w = (v.w != 0 || c0 + 3 == i) ? (ushort)0x3F80 : (ushort)0;
        cnt += (o.x != 0) + (o.y != 0) + (o.z != 0) + (o.w != 0);
        *(ushort4*)(prow + c0) = o;
    }
    for (int off = 32; off; off >>= 1) cnt += __shfl_down(cnt, off);
    if (lane == 0) dinv[rowg] = rsqrtf((float)cnt);
}

// ---------------------------------------------------------------------------
// transpose (R x C) -> (C x R) per z, optional per-input-row scale (dinv).
// INF32: input is float32 (weights); else input is bf16 ushort (ws buffers).
template<int INF32>
__global__ void transpose_scale_k(const void* __restrict__ in_, ushort* __restrict__ out,
                                  int R, int C, const float* __restrict__ scale, int scale_z) {
    __shared__ ushort tile[32][33];
    const long zo = (long)blockIdx.z * R * C;
    const int c0 = blockIdx.x * 32, r0 = blockIdx.y * 32;
    const int t = threadIdx.x;
    #pragma unroll
    for (int p = 0; p < 4; p++) {
        int e = p * 256 + t; int row = e >> 5, col = e & 31;
        long idx = zo + (long)(r0 + row) * C + c0 + col;
        float x = INF32 ? ((const float*)in_)[idx] : bf2f(((const ushort*)in_)[idx]);
        if (scale) x *= scale[(long)blockIdx.z * scale_z + r0 + row];
        tile[row][col] = f2bf(x);
    }
    __syncthreads();
    #pragma unroll
    for (int p = 0; p < 4; p++) {
        int e = p * 256 + t; int row = e >> 5, col = e & 31;   // row indexes C-dim now
        out[zo + (long)(c0 + row) * R + r0 + col] = tile[col][row];
    }
}

// ---------------------------------------------------------------------------
// Adjacency GEMM: C_part[ks][v] += Apack[v][m0:m0+128][kslice] @ Bt[v][0:128][kslice]^T
// 128x128 tile, BK=64, split-K=KSPLIT, global_load_lds(16B) staging into
// XOR-swizzled unpadded LDS (2-way bank alias only = free).
__global__ __launch_bounds__(256) void gemm_adj_k(
    const ushort* __restrict__ Apack,   // V x N x N bf16 {0,1}
    const ushort* __restrict__ Bt,      // V x 128 x N bf16 (K-contiguous)
    float* __restrict__ Cpart)          // KSPLIT x V x N x 128 f32
{
    __shared__ __align__(16) ushort As[128 * 64];
    __shared__ __align__(16) ushort Bs[128 * 64];
    const int tid = threadIdx.x, lane = tid & 63, w = tid >> 6;
    const int wr = w >> 1, wc = w & 1;
    const int ks = blockIdx.x, mt = blockIdx.y, z = blockIdx.z;
    const int m0 = mt * 128;
    const int kbeg = ks * (NN / KSPLIT);
    const ushort* Av = Apack + (long)z * NN * NN;
    const ushort* Bv = Bt + (long)z * 128 * NN;
    f32x4 acc[4][4] = {};

    int srow[4], slcb[4];
    #pragma unroll
    for (int p = 0; p < 4; p++) {
        int slot = (w * 4 + p) * 64 + lane;       // 0..1023, wave-contiguous
        srow[p] = slot >> 3;                       // tile row
        slcb[p] = (slot & 7) ^ (srow[p] & 7);      // logical 16B col-block (XOR swizzle)
    }

    for (int k0 = kbeg; k0 < kbeg + NN / KSPLIT; k0 += 64) {
        #pragma unroll
        for (int p = 0; p < 4; p++) {
            const int slot = (w * 4 + p) * 64 + lane;
            async_cp16(Av + (long)(m0 + srow[p]) * NN + k0 + slcb[p] * 8, As + slot * 8);
            async_cp16(Bv + (long)srow[p] * NN + k0 + slcb[p] * 8, Bs + slot * 8);
        }
        __syncthreads();
        #pragma unroll
        for (int s = 0; s < 2; s++) {
            bf16x8 af[4], bb[4];
            const int ca = s * 4 + (lane >> 4);
            #pragma unroll
            for (int mi = 0; mi < 4; mi++) {
                int r = wr * 64 + mi * 16 + (lane & 15);
                af[mi] = *(const bf16x8*)&As[r * 64 + ((ca ^ (r & 7)) * 8)];
            }
            #pragma unroll
            for (int ni = 0; ni < 4; ni++) {
                int r = wc * 64 + ni * 16 + (lane & 15);
                bb[ni] = *(const bf16x8*)&Bs[r * 64 + ((ca ^ (r & 7)) * 8)];
            }
            #pragma unroll
            for (int mi = 0; mi < 4; mi++)
                #pragma unroll
                for (int ni = 0; ni < 4; ni++)
                    acc[mi][ni] = __builtin_amdgcn_mfma_f32_16x16x32_bf16(af[mi], bb[ni], acc[mi][ni], 0, 0, 0);
        }
        __syncthreads();
    }

    float* C = Cpart + ((long)ks * VV + z) * ((long)NN * HH);
    #pragma unroll
    for (int mi = 0; mi < 4; mi++) {
        int rbase = m0 + wr * 64 + mi * 16 + ((lane >> 4) << 2);
        #pragma unroll
        for (int ni = 0; ni < 4; ni++) {
            int col = wc * 64 + ni * 16 + (lane & 15);
            #pragma unroll
            for (int r = 0; r < 4; r++)
                C[(long)(rbase + r) * HH + col] = acc[mi][ni][r];
        }
    }
}

// ---------------------------------------------------------------------------
// reduce KSPLIT partials + epilogue: h = relu(dinv[row]*sum + bias[v][col]),
// write bf16 (ws); WRITE_F32: also write f32 to fout (the h output region).
template<int WRITE_F32>
__global__ __launch_bounds__(256) void reduce_k(const float* __restrict__ P,
                                                const float* __restrict__ dinv,
                                                const float* __restrict__ bias,
                                                ushort* __restrict__ hout,
                                                float* __restrict__ fout) {
    const long e = ((long)blockIdx.x * 256 + threadIdx.x) * 4;
    const int v = (int)(e >> 20);                  // N*H = 2^20 per view
    const int n = (int)((e >> 7) & (NN - 1));
    const int col = (int)(e & 127);
    const long S = (long)VV * NN * HH;
    const float4 s0 = *(const float4*)(P + e);
    const float4 s1 = *(const float4*)(P + S + e);
    const float4 s2 = *(const float4*)(P + 2 * S + e);
    const float4 s3 = *(const float4*)(P + 3 * S + e);
    const float d = dinv[v * NN + n];
    const float r0 = fmaxf((s0.x + s1.x + s2.x + s3.x) * d + bias[v * HH + col + 0], 0.f);
    const float r1 = fmaxf((s0.y + s1.y + s2.y + s3.y) * d + bias[v * HH + col + 1], 0.f);
    const float r2 = fmaxf((s0.z + s1.z + s2.z + s3.z) * d + bias[v * HH + col + 2], 0.f);
    const float r3 = fmaxf((s0.w + s1.w + s2.w + s3.w) * d + bias[v * HH + col + 3], 0.f);
    ushort4 o; o.x = f2bf(r0); o.y = f2bf(r1); o.z = f2bf(r2); o.w = f2bf(r3);
    *(ushort4*)(hout + e) = o;
    if (WRITE_F32) { float4 f; f.x = r0; f.y = r1; f.z = r2; f.w = r3; *(float4*)(fout + e) = f; }
}

// ---------------------------------------------------------------------------
// Generic 128x128-tile MFMA GEMM (round-2 validated) for the small GEMMs.
// AMODE 1: A = bf16 row-major (ws), lda given
// AMODE 2: A = h (V,N,H) bf16 (ws), K runs over v*H+h', scaled by attn[v]
// EPI 1: dinv[row]*acc ; EPI 2: relu(acc + bias[col]) ; EPI 3: acc + bias[col]
template<int AMODE, int EPI, int OUTF32>
__global__ __launch_bounds__(256) void gemm_k(
    const void* __restrict__ Aany, long a_zs, int lda,
    const ushort* __restrict__ Bt, long b_zs, int ldb,
    void* __restrict__ Cc, long c_zs, int ldc,
    int Ktot,
    const float* __restrict__ dinv, int dinv_zs,
    const float* __restrict__ bias, int bias_zs,
    const float* __restrict__ attnp)
{
    __shared__ __align__(16) ushort As[128][40];
    __shared__ __align__(16) ushort Bs[128][40];
    const int tid = threadIdx.x;
    const int bx = blockIdx.x, by = blockIdx.y, z = blockIdx.z;
    const int m0 = by * 128, n0 = bx * 128;
    const int lane = tid & 63, w = tid >> 6, wr = w >> 1, wc = w & 1;
    f32x4 acc[4][4] = {};
    float att0 = 0.f, att1 = 0.f, att2 = 0.f;
    if (AMODE == 2) { att0 = attnp[0]; att1 = attnp[1]; att2 = attnp[2]; }
    const ushort* Ab = (const ushort*)Aany + (long)z * (AMODE == 1 ? a_zs : 0);
    const ushort* Btz = Bt + (long)z * b_zs;

    for (int k0 = 0; k0 < Ktot; k0 += 32) {
        if (AMODE == 1) {
            #pragma unroll
            for (int p = 0; p < 2; p++) {
                int c = p * 256 + tid;
                int row = c >> 2, q = c & 3;
                *(int4*)&As[row][q * 8] = *(const int4*)(Ab + (long)(m0 + row) * lda + k0 + q * 8);
            }
        } else {
            #pragma unroll
            for (int p = 0; p < 2; p++) {
                int c = p * 256 + tid;
                int row = c >> 2, q = c & 3;
                int kk = k0 + q * 8;
                int v = kk >> 7, ko = kk & 127;
                int4 raw = *(const int4*)((const ushort*)Aany + (long)v * a_zs + (long)(m0 + row) * HH + ko);
                float sc = (v == 0) ? att0 : (v == 1 ? att1 : att2);
                __align__(16) ushort us[8];
                *(int4*)us = raw;
                #pragma unroll
                for (int e = 0; e < 8; e++) us[e] = f2bf(bf2f(us[e]) * sc);
                *(int4*)&As[row][q * 8] = *(int4*)us;
            }
        }
        #pragma unroll
        for (int p = 0; p < 2; p++) {
            int c = p * 256 + tid;
            int n = c >> 2, q = c & 3;
            *(int4*)&Bs[n][q * 8] = *(const int4*)(Btz + (long)(n0 + n) * ldb + k0 + q * 8);
        }
        __syncthreads();
        bf16x8 af[4], bfr[4];
        #pragma unroll
        for (int mi = 0; mi < 4; mi++)
            af[mi] = *(const bf16x8*)&As[wr * 64 + mi * 16 + (lane & 15)][(lane >> 4) * 8];
        #pragma unroll
        for (int ni = 0; ni < 4; ni++)
            bfr[ni] = *(const bf16x8*)&Bs[wc * 64 + ni * 16 + (lane & 15)][(lane >> 4) * 8];
        #pragma unroll
        for (int mi = 0; mi < 4; mi++)
            #pragma unroll
            for (int ni = 0; ni < 4; ni++)
                acc[mi][ni] = __builtin_amdgcn_mfma_f32_16x16x32_bf16(af[mi], bfr[ni], acc[mi][ni], 0, 0, 0);
        __syncthreads();
    }

    #pragma unroll
    for (int mi = 0; mi < 4; mi++) {
        int rbase = m0 + wr * 64 + mi * 16 + ((lane >> 4) << 2);
        #pragma unroll
        for (int ni = 0; ni < 4; ni++) {
            int col = n0 + wc * 64 + ni * 16 + (lane & 15);
            #pragma unroll
            for (int r = 0; r < 4; r++) {
                int grow = rbase + r;
                float vv = acc[mi][ni][r];
                if (EPI == 1) vv *= dinv[(long)z * dinv_zs + grow];
                if (EPI == 2 || EPI == 3) vv += bias[col];
                if (EPI == 2) vv = fmaxf(vv, 0.0f);
                if (OUTF32) ((float*)Cc + (long)z * c_zs)[(long)grow * ldc + col] = vv;
                else        ((ushort*)Cc + (long)z * c_zs)[(long)grow * ldc + col] = f2bf(vv);
            }
        }
    }
}

// ---------------------------------------------------------------------------
// column sums of h2 (bf16 ws) into summ[v*H+col]
__global__ __launch_bounds__(256) void colsum_k(const ushort* __restrict__ h2,
                                                float* __restrict__ summ) {
    const int rowbase = blockIdx.x * 64;
    const int z = rowbase >> 13;
    const int col = threadIdx.x & 127, half = threadIdx.x >> 7;
    float s = 0.0f;
    for (int r = half; r < 64; r += 2) s += bf2f(h2[(long)(rowbase + r) * HH + col]);
    atomicAdd(&summ[z * HH + col], s);
}

// ---------------------------------------------------------------------------
// attention: summ(sum)/N -> tanh(@Wa1+ba1)@Wa2+ba2 -> softmax over V
__global__ __launch_bounds__(256) void attn_k(const float* __restrict__ summ,
                                              const float* __restrict__ Wa1,
                                              const float* __restrict__ ba1,
                                              const float* __restrict__ Wa2,
                                              const float* __restrict__ ba2,
                                              float* __restrict__ attnws,
                                              float* __restrict__ out_attn) {
    __shared__ float sc[VV];
    const int tid = threadIdx.x;
    if (tid < VV * 64) {
        const int v = tid >> 6, a = tid & 63;
        float s = ba1[a];
        const float invN = 1.0f / (float)NN;
        #pragma unroll 4
        for (int h = 0; h < HH; h++) s += summ[v * HH + h] * invN * Wa1[h * ADIM + a];
        float p = tanhf(s) * Wa2[a];
        for (int off = 32; off; off >>= 1) p += __shfl_down(p, off);
        if (a == 0) sc[v] = p + ba2[0];
    }
    __syncthreads();
    if (tid == 0) {
        float m = fmaxf(sc[0], fmaxf(sc[1], sc[2]));
        float e0 = expf(sc[0] - m), e1 = expf(sc[1] - m), e2 = expf(sc[2] - m);
        float inv = 1.0f / (e0 + e1 + e2);
        attnws[0] = e0 * inv; attnws[1] = e1 * inv; attnws[2] = e2 * inv;
        out_attn[0] = e0 * inv; out_attn[1] = e1 * inv; out_attn[2] = e2 * inv;
    }
}

// ---------------------------------------------------------------------------
extern "C" void kernel_launch(void* const* d_in, const int* in_sizes, int n_in,
                              void* d_out, int out_size, void* d_ws, size_t ws_size,
                              hipStream_t stream) {
    const int*   adj = (const int*)d_in[0];
    const float* W1  = (const float*)d_in[1];
    const float* b1  = (const float*)d_in[2];
    const float* W2  = (const float*)d_in[3];
    const float* b2  = (const float*)d_in[4];
    const float* Wa1 = (const float*)d_in[5];
    const float* ba1 = (const float*)d_in[6];
    const float* Wa2 = (const float*)d_in[7];
    const float* ba2 = (const float*)d_in[8];
    const float* Wf1 = (const float*)d_in[9];
    const float* bf1 = (const float*)d_in[10];
    const float* Wf2 = (const float*)d_in[11];
    const float* bf2v = (const float*)d_in[12];

    float* out = (float*)d_out;
    float* out_fused = out;                                  // (N, FOUT)
    float* out_attn  = out + (long)NN * FOUT;                // (V,)
    float* out_h     = out + (long)NN * FOUT + VV;           // (V,N,H)

    char* wsb = (char*)d_ws;
    const long SZ_DINV  = (long)VV * NN * 4;                 // 98304
    const long SZ_APACK = (long)VV * NN * NN * 2;            // 402653184
    const long SZ_W1T   = (long)VV * HH * NN * 2;            // 6291456
    const long SZ_W2T   = (long)VV * HH * HH * 2;            // 98304
    const long SZ_WF1T  = 256L * 384 * 2;                    // 196608
    const long SZ_WF2T  = 128L * 256 * 2;                    // 65536
    const long SZ_VNH   = (long)VV * NN * HH * 2;            // 6291456
    const long SZ_PART  = (long)KSPLIT * VV * NN * HH * 4;   // 50331648
    const long SZ_G     = (long)NN * 256 * 2;                // 4194304
    long off = 0;
    float*  dinv  = (float*)(wsb + off);  off += SZ_DINV;
    ushort* apack = (ushort*)(wsb + off); off += SZ_APACK;
    ushort* w1t   = (ushort*)(wsb + off); off += SZ_W1T;
    ushort* w2t   = (ushort*)(wsb + off); off += SZ_W2T;
    ushort* wf1t  = (ushort*)(wsb + off); off += SZ_WF1T;
    ushort* wf2t  = (ushort*)(wsb + off); off += SZ_WF2T;
    ushort* h1    = (ushort*)(wsb + off); off += SZ_VNH;
    ushort* tbuf  = (ushort*)(wsb + off); off += SZ_VNH;
    ushort* tT    = (ushort*)(wsb + off); off += SZ_VNH;
    ushort* h2    = (ushort*)(wsb + off); off += SZ_VNH;
    float*  cpart = (float*)(wsb + off);  off += SZ_PART;
    ushort* G     = (ushort*)(wsb + off); off += SZ_G;
    float*  summ  = (float*)(wsb + off);  off += 1536;
    float*  attnw = (float*)(wsb + off);  off += 16;

    const long VNH = (long)NN * HH;

    // 1) zero summ scratch
    zero_k<<<1, 512, 0, stream>>>(summ, 388);
    // 2) fused deg + bf16 pack of adjacency
    pack_k<<<(VV * NN) / 4, 256, 0, stream>>>(adj, apack, dinv);
    // 3) weight transposes (B operands staged as (Ncols x K) row-major, bf16)
    transpose_scale_k<1><<<dim3(4, 256, VV), 256, 0, stream>>>(W1, w1t, NN, HH, dinv, NN);
    transpose_scale_k<1><<<dim3(4, 4, VV), 256, 0, stream>>>(W2, w2t, HH, HH, nullptr, 0);
    transpose_scale_k<1><<<dim3(8, 12, 1), 256, 0, stream>>>(Wf1, wf1t, 384, 256, nullptr, 0);
    transpose_scale_k<1><<<dim3(4, 8, 1), 256, 0, stream>>>(Wf2, wf2t, 256, 128, nullptr, 0);
    // 4) GEMM1 partials: Apack @ (dinv_j*W1)
    gemm_adj_k<<<dim3(KSPLIT, 64, VV), 256, 0, stream>>>(apack, w1t, cpart);
    // 5) h1 = relu(dinv_i * sum + b1)
    reduce_k<0><<<3072, 256, 0, stream>>>(cpart, dinv, b1, h1, nullptr);
    // 6) t = dinv_k * (h1 @ W2)
    gemm_k<1, 1, 0><<<dim3(1, 64, VV), 256, 0, stream>>>(h1, VNH, HH, w2t, (long)HH * HH, HH,
                                                         tbuf, VNH, HH, HH, dinv, NN, nullptr, 0, nullptr);
    // 7) tT[v][n][k] = t[v][k][n]
    transpose_scale_k<0><<<dim3(4, 256, VV), 256, 0, stream>>>(tbuf, tT, NN, HH, nullptr, 0);
    // 8) GEMM2 partials: Apack @ t
    gemm_adj_k<<<dim3(KSPLIT, 64, VV), 256, 0, stream>>>(apack, tT, cpart);
    // 9) h2 = relu(dinv_i * sum + b2) -> bf16 ws + f32 out
    reduce_k<1><<<3072, 256, 0, stream>>>(cpart, dinv, b2, h2, out_h);
    // 10) column sums for attention
    colsum_k<<<(VV * NN) / 64, 256, 0, stream>>>(h2, summ);
    // 11) attention weights
    attn_k<<<1, 256, 0, stream>>>(summ, Wa1, ba1, Wa2, ba2, attnw, out_attn);
    // 12) G = relu([attn_v*h_v] @ Wf1 + bf1)   (M=8192, K=384, Ncols=256)
    gemm_k<2, 2, 0><<<dim3(2, 64, 1), 256, 0, stream>>>(h2, VNH, HH, wf1t, 0, 384,
                                                        G, 0, 256, 384, nullptr, 0, bf1, 0, attnw);
    // 13) fused = G @ Wf2 + bf2                (M=8192, K=256, Ncols=128)
    gemm_k<1, 3, 1><<<dim3(1, 64, 1), 256, 0, stream>>>(G, 0, 256, wf2t, 0, 256,
                                                        out_fused, 0, FOUT, 256, nullptr, 0, bf2v, 0, nullptr);
}

// Round 4
// 1407.331 us; speedup vs baseline: 1.2773x; 1.0322x over previous
//
#include <hip/hip_runtime.h>
#include <hip/hip_bf16.h>

// Problem constants
#define VV 3
#define NN 8192
#define HH 128
#define ADIM 64
#define FOUT 128
#define KSPLIT 4

typedef short bf16x8 __attribute__((ext_vector_type(8)));
typedef float f32x4 __attribute__((ext_vector_type(4)));

__device__ __forceinline__ float bf2f(ushort u) {
    union { unsigned int i; float f; } x; x.i = ((unsigned int)u) << 16; return x.f;
}
__device__ __forceinline__ ushort f2bf(float f) {
    union { float f; unsigned int i; } x; x.f = f;
    unsigned int r = (x.i + 0x7FFFu + ((x.i >> 16) & 1u)) >> 16;
    return (ushort)r;
}
__device__ __forceinline__ void async_cp16(const ushort* g, ushort* l) {
    __builtin_amdgcn_global_load_lds(
        (const __attribute__((address_space(1))) void*)g,
        (__attribute__((address_space(3))) void*)l, 16, 0, 0);
}

// ---------------------------------------------------------------------------
// zero a small float region (summ scratch); ws is poisoned every call
__global__ void zero_k(float* p, int n) {
    int i = blockIdx.x * blockDim.x + threadIdx.x;
    if (i < n) p[i] = 0.0f;
}

// ---------------------------------------------------------------------------
// fused deg + pack into GEMM-staging-tiled layout:
//   chunk index = (z*64+mt)*128 + c   (16 KB chunks: 128 rows x 64 cols)
//   within chunk: elem (r, q*8+e) stored at r*64 + ((q^(r&7))*8) + e
// so gemm_adj A-staging reads are perfectly contiguous per wave instruction.
// dinv[v*N+i] = rsqrt(row_sum with forced diag=1). One wave per source row.
__global__ __launch_bounds__(256) void pack_k(const int* __restrict__ adj,
                                              ushort* __restrict__ apackT,
                                              float* __restrict__ dinv) {
    const int w = threadIdx.x >> 6, lane = threadIdx.x & 63;
    const long rowg = (long)blockIdx.x * 4 + w;              // z*N + n
    const int n = (int)(rowg & (NN - 1));
    const int r = n & 127, rsw = r & 7, roff = r * 64;
    const long tilebase = (rowg >> 7) * (128L * 8192);       // (z*64+mt)*128 chunks
    const int* row = adj + rowg * NN;
    int cnt = 0;
    #pragma unroll 4
    for (int it = 0; it < 32; it++) {
        const int c0 = it * 256 + lane * 4;                  // source col of .x
        const int4 v = *(const int4*)(row + c0);
        ushort4 o;
        o.x = (v.x != 0 || c0 + 0 == n) ? (ushort)0x3F80 : (ushort)0;
        o.y = (v.y != 0 || c0 + 1 == n) ? (ushort)0x3F80 : (ushort)0;
        o.z = (v.z != 0 || c0 + 2 == n) ? (ushort)0x3F80 : (ushort)0;
        o.w = (v.w != 0 || c0 + 3 == n) ? (ushort)0x3F80 : (ushort)0;
        cnt += (o.x != 0) + (o.y != 0) + (o.z != 0) + (o.w != 0);
        const int c = c0 >> 6, cc = c0 & 63, q = cc >> 3, e = cc & 7;   // e in {0,4}
        *(ushort4*)(apackT + tilebase + (long)c * 8192 + roff + ((q ^ rsw) * 8) + e) = o;
    }
    for (int off = 32; off; off >>= 1) cnt += __shfl_down(cnt, off);
    if (lane == 0) dinv[rowg] = rsqrtf((float)cnt);
}

// ---------------------------------------------------------------------------
// transpose (R x C) -> (C x R) per z, optional per-input-row scale (dinv).
// INF32: input is float32 (weights); else input is bf16 ushort (ws buffers).
template<int INF32>
__global__ void transpose_scale_k(const void* __restrict__ in_, ushort* __restrict__ out,
                                  int R, int C, const float* __restrict__ scale, int scale_z) {
    __shared__ ushort tile[32][33];
    const long zo = (long)blockIdx.z * R * C;
    const int c0 = blockIdx.x * 32, r0 = blockIdx.y * 32;
    const int t = threadIdx.x;
    #pragma unroll
    for (int p = 0; p < 4; p++) {
        int e = p * 256 + t; int row = e >> 5, col = e & 31;
        long idx = zo + (long)(r0 + row) * C + c0 + col;
        float x = INF32 ? ((const float*)in_)[idx] : bf2f(((const ushort*)in_)[idx]);
        if (scale) x *= scale[(long)blockIdx.z * scale_z + r0 + row];
        tile[row][col] = f2bf(x);
    }
    __syncthreads();
    #pragma unroll
    for (int p = 0; p < 4; p++) {
        int e = p * 256 + t; int row = e >> 5, col = e & 31;   // row indexes C-dim now
        out[zo + (long)(c0 + row) * R + r0 + col] = tile[col][row];
    }
}

// ---------------------------------------------------------------------------
// Adjacency GEMM: Cpart[ks][v] = ApackT-tile @ Bt[v][0:128][kslice]^T
// 128x128 tile, BK=64, split-K=KSPLIT. A staging = contiguous 1 KB per wave
// instruction (layout pre-tiled+swizzled by pack_k); B staged with XOR
// swizzle computed on the global side (L2-resident).
__global__ __launch_bounds__(256) void gemm_adj_k(
    const ushort* __restrict__ ApackT,  // tiled, see pack_k
    const ushort* __restrict__ Bt,      // V x 128 x N bf16 (K-contiguous)
    float* __restrict__ Cpart)          // KSPLIT x V x N x 128 f32
{
    __shared__ __align__(16) ushort As[128 * 64];
    __shared__ __align__(16) ushort Bs[128 * 64];
    const int tid = threadIdx.x, lane = tid & 63, w = tid >> 6;
    const int wr = w >> 1, wc = w & 1;
    const int ks = blockIdx.x, mt = blockIdx.y, z = blockIdx.z;
    const int m0 = mt * 128;
    const int kbeg = ks * (NN / KSPLIT);
    const ushort* Atile = ApackT + ((long)(z * 64 + mt) * 128) * 8192;
    const ushort* Bv = Bt + (long)z * 128 * NN;
    f32x4 acc[4][4] = {};

    int srow[4], slcb[4];
    #pragma unroll
    for (int p = 0; p < 4; p++) {
        int slot = (w * 4 + p) * 64 + lane;       // 0..1023, wave-contiguous
        srow[p] = slot >> 3;                       // tile row
        slcb[p] = (slot & 7) ^ (srow[p] & 7);      // logical 16B col-block (XOR swizzle)
    }

    for (int k0 = kbeg; k0 < kbeg + NN / KSPLIT; k0 += 64) {
        const ushort* Achunk = Atile + (long)(k0 >> 6) * 8192;
        #pragma unroll
        for (int p = 0; p < 4; p++) {
            const int slot = (w * 4 + p) * 64 + lane;
            async_cp16(Achunk + slot * 8, As + slot * 8);
            async_cp16(Bv + (long)srow[p] * NN + k0 + slcb[p] * 8, Bs + slot * 8);
        }
        __syncthreads();
        #pragma unroll
        for (int s = 0; s < 2; s++) {
            bf16x8 af[4], bb[4];
            const int ca = s * 4 + (lane >> 4);
            #pragma unroll
            for (int mi = 0; mi < 4; mi++) {
                int r = wr * 64 + mi * 16 + (lane & 15);
                af[mi] = *(const bf16x8*)&As[r * 64 + ((ca ^ (r & 7)) * 8)];
            }
            #pragma unroll
            for (int ni = 0; ni < 4; ni++) {
                int r = wc * 64 + ni * 16 + (lane & 15);
                bb[ni] = *(const bf16x8*)&Bs[r * 64 + ((ca ^ (r & 7)) * 8)];
            }
            #pragma unroll
            for (int mi = 0; mi < 4; mi++)
                #pragma unroll
                for (int ni = 0; ni < 4; ni++)
                    acc[mi][ni] = __builtin_amdgcn_mfma_f32_16x16x32_bf16(af[mi], bb[ni], acc[mi][ni], 0, 0, 0);
        }
        __syncthreads();
    }

    float* C = Cpart + ((long)ks * VV + z) * ((long)NN * HH);
    #pragma unroll
    for (int mi = 0; mi < 4; mi++) {
        int rbase = m0 + wr * 64 + mi * 16 + ((lane >> 4) << 2);
        #pragma unroll
        for (int ni = 0; ni < 4; ni++) {
            int col = wc * 64 + ni * 16 + (lane & 15);
            #pragma unroll
            for (int r = 0; r < 4; r++)
                C[(long)(rbase + r) * HH + col] = acc[mi][ni][r];
        }
    }
}

// ---------------------------------------------------------------------------
// reduce KSPLIT partials + epilogue: h = relu(dinv[row]*sum + bias[v][col]),
// write bf16 (ws); WRITE_F32: also write f32 to fout (the h output region).
template<int WRITE_F32>
__global__ __launch_bounds__(256) void reduce_k(const float* __restrict__ P,
                                                const float* __restrict__ dinv,
                                                const float* __restrict__ bias,
                                                ushort* __restrict__ hout,
                                                float* __restrict__ fout) {
    const long e = ((long)blockIdx.x * 256 + threadIdx.x) * 4;
    const int v = (int)(e >> 20);                  // N*H = 2^20 per view
    const int n = (int)((e >> 7) & (NN - 1));
    const int col = (int)(e & 127);
    const long S = (long)VV * NN * HH;
    const float4 s0 = *(const float4*)(P + e);
    const float4 s1 = *(const float4*)(P + S + e);
    const float4 s2 = *(const float4*)(P + 2 * S + e);
    const float4 s3 = *(const float4*)(P + 3 * S + e);
    const float d = dinv[v * NN + n];
    const float r0 = fmaxf((s0.x + s1.x + s2.x + s3.x) * d + bias[v * HH + col + 0], 0.f);
    const float r1 = fmaxf((s0.y + s1.y + s2.y + s3.y) * d + bias[v * HH + col + 1], 0.f);
    const float r2 = fmaxf((s0.z + s1.z + s2.z + s3.z) * d + bias[v * HH + col + 2], 0.f);
    const float r3 = fmaxf((s0.w + s1.w + s2.w + s3.w) * d + bias[v * HH + col + 3], 0.f);
    ushort4 o; o.x = f2bf(r0); o.y = f2bf(r1); o.z = f2bf(r2); o.w = f2bf(r3);
    *(ushort4*)(hout + e) = o;
    if (WRITE_F32) { float4 f; f.x = r0; f.y = r1; f.z = r2; f.w = r3; *(float4*)(fout + e) = f; }
}

// ---------------------------------------------------------------------------
// Generic 128x128-tile MFMA GEMM for the small GEMMs.
// AMODE 1: A = bf16 row-major (ws), lda given
// AMODE 2: A = h (V,N,H) bf16 (ws), K runs over v*H+h', scaled by attn[v]
// EPI 1: dinv[row]*acc ; EPI 2: relu(acc + bias[col]) ; EPI 3: acc + bias[col]
template<int AMODE, int EPI, int OUTF32>
__global__ __launch_bounds__(256) void gemm_k(
    const void* __restrict__ Aany, long a_zs, int lda,
    const ushort* __restrict__ Bt, long b_zs, int ldb,
    void* __restrict__ Cc, long c_zs, int ldc,
    int Ktot,
    const float* __restrict__ dinv, int dinv_zs,
    const float* __restrict__ bias, int bias_zs,
    const float* __restrict__ attnp)
{
    __shared__ __align__(16) ushort As[128][40];
    __shared__ __align__(16) ushort Bs[128][40];
    const int tid = threadIdx.x;
    const int bx = blockIdx.x, by = blockIdx.y, z = blockIdx.z;
    const int m0 = by * 128, n0 = bx * 128;
    const int lane = tid & 63, w = tid >> 6, wr = w >> 1, wc = w & 1;
    f32x4 acc[4][4] = {};
    float att0 = 0.f, att1 = 0.f, att2 = 0.f;
    if (AMODE == 2) { att0 = attnp[0]; att1 = attnp[1]; att2 = attnp[2]; }
    const ushort* Ab = (const ushort*)Aany + (long)z * (AMODE == 1 ? a_zs : 0);
    const ushort* Btz = Bt + (long)z * b_zs;

    for (int k0 = 0; k0 < Ktot; k0 += 32) {
        if (AMODE == 1) {
            #pragma unroll
            for (int p = 0; p < 2; p++) {
                int c = p * 256 + tid;
                int row = c >> 2, q = c & 3;
                *(int4*)&As[row][q * 8] = *(const int4*)(Ab + (long)(m0 + row) * lda + k0 + q * 8);
            }
        } else {
            #pragma unroll
            for (int p = 0; p < 2; p++) {
                int c = p * 256 + tid;
                int row = c >> 2, q = c & 3;
                int kk = k0 + q * 8;
                int v = kk >> 7, ko = kk & 127;
                int4 raw = *(const int4*)((const ushort*)Aany + (long)v * a_zs + (long)(m0 + row) * HH + ko);
                float sc = (v == 0) ? att0 : (v == 1 ? att1 : att2);
                __align__(16) ushort us[8];
                *(int4*)us = raw;
                #pragma unroll
                for (int e = 0; e < 8; e++) us[e] = f2bf(bf2f(us[e]) * sc);
                *(int4*)&As[row][q * 8] = *(int4*)us;
            }
        }
        #pragma unroll
        for (int p = 0; p < 2; p++) {
            int c = p * 256 + tid;
            int n = c >> 2, q = c & 3;
            *(int4*)&Bs[n][q * 8] = *(const int4*)(Btz + (long)(n0 + n) * ldb + k0 + q * 8);
        }
        __syncthreads();
        bf16x8 af[4], bfr[4];
        #pragma unroll
        for (int mi = 0; mi < 4; mi++)
            af[mi] = *(const bf16x8*)&As[wr * 64 + mi * 16 + (lane & 15)][(lane >> 4) * 8];
        #pragma unroll
        for (int ni = 0; ni < 4; ni++)
            bfr[ni] = *(const bf16x8*)&Bs[wc * 64 + ni * 16 + (lane & 15)][(lane >> 4) * 8];
        #pragma unroll
        for (int mi = 0; mi < 4; mi++)
            #pragma unroll
            for (int ni = 0; ni < 4; ni++)
                acc[mi][ni] = __builtin_amdgcn_mfma_f32_16x16x32_bf16(af[mi], bfr[ni], acc[mi][ni], 0, 0, 0);
        __syncthreads();
    }

    #pragma unroll
    for (int mi = 0; mi < 4; mi++) {
        int rbase = m0 + wr * 64 + mi * 16 + ((lane >> 4) << 2);
        #pragma unroll
        for (int ni = 0; ni < 4; ni++) {
            int col = n0 + wc * 64 + ni * 16 + (lane & 15);
            #pragma unroll
            for (int r = 0; r < 4; r++) {
                int grow = rbase + r;
                float vv = acc[mi][ni][r];
                if (EPI == 1) vv *= dinv[(long)z * dinv_zs + grow];
                if (EPI == 2 || EPI == 3) vv += bias[col];
                if (EPI == 2) vv = fmaxf(vv, 0.0f);
                if (OUTF32) ((float*)Cc + (long)z * c_zs)[(long)grow * ldc + col] = vv;
                else        ((ushort*)Cc + (long)z * c_zs)[(long)grow * ldc + col] = f2bf(vv);
            }
        }
    }
}

// ---------------------------------------------------------------------------
// column sums of h2 (bf16 ws) into summ[v*H+col]
__global__ __launch_bounds__(256) void colsum_k(const ushort* __restrict__ h2,
                                                float* __restrict__ summ) {
    const int rowbase = blockIdx.x * 64;
    const int z = rowbase >> 13;
    const int col = threadIdx.x & 127, half = threadIdx.x >> 7;
    float s = 0.0f;
    for (int r = half; r < 64; r += 2) s += bf2f(h2[(long)(rowbase + r) * HH + col]);
    atomicAdd(&summ[z * HH + col], s);
}

// ---------------------------------------------------------------------------
// attention: summ(sum)/N -> tanh(@Wa1+ba1)@Wa2+ba2 -> softmax over V
__global__ __launch_bounds__(256) void attn_k(const float* __restrict__ summ,
                                              const float* __restrict__ Wa1,
                                              const float* __restrict__ ba1,
                                              const float* __restrict__ Wa2,
                                              const float* __restrict__ ba2,
                                              float* __restrict__ attnws,
                                              float* __restrict__ out_attn) {
    __shared__ float sc[VV];
    const int tid = threadIdx.x;
    if (tid < VV * 64) {
        const int v = tid >> 6, a = tid & 63;
        float s = ba1[a];
        const float invN = 1.0f / (float)NN;
        #pragma unroll 4
        for (int h = 0; h < HH; h++) s += summ[v * HH + h] * invN * Wa1[h * ADIM + a];
        float p = tanhf(s) * Wa2[a];
        for (int off = 32; off; off >>= 1) p += __shfl_down(p, off);
        if (a == 0) sc[v] = p + ba2[0];
    }
    __syncthreads();
    if (tid == 0) {
        float m = fmaxf(sc[0], fmaxf(sc[1], sc[2]));
        float e0 = expf(sc[0] - m), e1 = expf(sc[1] - m), e2 = expf(sc[2] - m);
        float inv = 1.0f / (e0 + e1 + e2);
        attnws[0] = e0 * inv; attnws[1] = e1 * inv; attnws[2] = e2 * inv;
        out_attn[0] = e0 * inv; out_attn[1] = e1 * inv; out_attn[2] = e2 * inv;
    }
}

// ---------------------------------------------------------------------------
extern "C" void kernel_launch(void* const* d_in, const int* in_sizes, int n_in,
                              void* d_out, int out_size, void* d_ws, size_t ws_size,
                              hipStream_t stream) {
    const int*   adj = (const int*)d_in[0];
    const float* W1  = (const float*)d_in[1];
    const float* b1  = (const float*)d_in[2];
    const float* W2  = (const float*)d_in[3];
    const float* b2  = (const float*)d_in[4];
    const float* Wa1 = (const float*)d_in[5];
    const float* ba1 = (const float*)d_in[6];
    const float* Wa2 = (const float*)d_in[7];
    const float* ba2 = (const float*)d_in[8];
    const float* Wf1 = (const float*)d_in[9];
    const float* bf1 = (const float*)d_in[10];
    const float* Wf2 = (const float*)d_in[11];
    const float* bf2v = (const float*)d_in[12];

    float* out = (float*)d_out;
    float* out_fused = out;                                  // (N, FOUT)
    float* out_attn  = out + (long)NN * FOUT;                // (V,)
    float* out_h     = out + (long)NN * FOUT + VV;           // (V,N,H)

    char* wsb = (char*)d_ws;
    const long SZ_DINV  = (long)VV * NN * 4;                 // 98304
    const long SZ_APACK = (long)VV * NN * NN * 2;            // 402653184
    const long SZ_W1T   = (long)VV * HH * NN * 2;            // 6291456
    const long SZ_W2T   = (long)VV * HH * HH * 2;            // 98304
    const long SZ_WF1T  = 256L * 384 * 2;                    // 196608
    const long SZ_WF2T  = 128L * 256 * 2;                    // 65536
    const long SZ_VNH   = (long)VV * NN * HH * 2;            // 6291456
    const long SZ_PART  = (long)KSPLIT * VV * NN * HH * 4;   // 50331648
    const long SZ_G     = (long)NN * 256 * 2;                // 4194304
    long off = 0;
    float*  dinv  = (float*)(wsb + off);  off += SZ_DINV;
    ushort* apack = (ushort*)(wsb + off); off += SZ_APACK;
    ushort* w1t   = (ushort*)(wsb + off); off += SZ_W1T;
    ushort* w2t   = (ushort*)(wsb + off); off += SZ_W2T;
    ushort* wf1t  = (ushort*)(wsb + off); off += SZ_WF1T;
    ushort* wf2t  = (ushort*)(wsb + off); off += SZ_WF2T;
    ushort* h1    = (ushort*)(wsb + off); off += SZ_VNH;
    ushort* tbuf  = (ushort*)(wsb + off); off += SZ_VNH;
    ushort* tT    = (ushort*)(wsb + off); off += SZ_VNH;
    ushort* h2    = (ushort*)(wsb + off); off += SZ_VNH;
    float*  cpart = (float*)(wsb + off);  off += SZ_PART;
    ushort* G     = (ushort*)(wsb + off); off += SZ_G;
    float*  summ  = (float*)(wsb + off);  off += 1536;
    float*  attnw = (float*)(wsb + off);  off += 16;

    const long VNH = (long)NN * HH;

    // 1) zero summ scratch
    zero_k<<<1, 512, 0, stream>>>(summ, 388);
    // 2) fused deg + bf16 pack of adjacency (tiled+swizzled layout)
    pack_k<<<(VV * NN) / 4, 256, 0, stream>>>(adj, apack, dinv);
    // 3) weight transposes (B operands staged as (Ncols x K) row-major, bf16)
    transpose_scale_k<1><<<dim3(4, 256, VV), 256, 0, stream>>>(W1, w1t, NN, HH, dinv, NN);
    transpose_scale_k<1><<<dim3(4, 4, VV), 256, 0, stream>>>(W2, w2t, HH, HH, nullptr, 0);
    transpose_scale_k<1><<<dim3(8, 12, 1), 256, 0, stream>>>(Wf1, wf1t, 384, 256, nullptr, 0);
    transpose_scale_k<1><<<dim3(4, 8, 1), 256, 0, stream>>>(Wf2, wf2t, 256, 128, nullptr, 0);
    // 4) GEMM1 partials: Apack @ (dinv_j*W1)
    gemm_adj_k<<<dim3(KSPLIT, 64, VV), 256, 0, stream>>>(apack, w1t, cpart);
    // 5) h1 = relu(dinv_i * sum + b1)
    reduce_k<0><<<3072, 256, 0, stream>>>(cpart, dinv, b1, h1, nullptr);
    // 6) t = dinv_k * (h1 @ W2)
    gemm_k<1, 1, 0><<<dim3(1, 64, VV), 256, 0, stream>>>(h1, VNH, HH, w2t, (long)HH * HH, HH,
                                                         tbuf, VNH, HH, HH, dinv, NN, nullptr, 0, nullptr);
    // 7) tT[v][n][k] = t[v][k][n]
    transpose_scale_k<0><<<dim3(4, 256, VV), 256, 0, stream>>>(tbuf, tT, NN, HH, nullptr, 0);
    // 8) GEMM2 partials: Apack @ t
    gemm_adj_k<<<dim3(KSPLIT, 64, VV), 256, 0, stream>>>(apack, tT, cpart);
    // 9) h2 = relu(dinv_i * sum + b2) -> bf16 ws + f32 out
    reduce_k<1><<<3072, 256, 0, stream>>>(cpart, dinv, b2, h2, out_h);
    // 10) column sums for attention
    colsum_k<<<(VV * NN) / 64, 256, 0, stream>>>(h2, summ);
    // 11) attention weights
    attn_k<<<1, 256, 0, stream>>>(summ, Wa1, ba1, Wa2, ba2, attnw, out_attn);
    // 12) G = relu([attn_v*h_v] @ Wf1 + bf1)   (M=8192, K=384, Ncols=256)
    gemm_k<2, 2, 0><<<dim3(2, 64, 1), 256, 0, stream>>>(h2, VNH, HH, wf1t, 0, 384,
                                                        G, 0, 256, 384, nullptr, 0, bf1, 0, attnw);
    // 13) fused = G @ Wf2 + bf2                (M=8192, K=256, Ncols=128)
    gemm_k<1, 3, 1><<<dim3(1, 64, 1), 256, 0, stream>>>(G, 0, 256, wf2t, 0, 256,
                                                        out_fused, 0, FOUT, 256, nullptr, 0, bf2v, 0, nullptr);
}